// Round 6
// baseline (253.951 us; speedup 1.0000x reference)
//
#include <hip/hip_runtime.h>
#include <stdint.h>

// B=2, T=2048, C=768, H=12, D=64. All inputs fp32; output fp32.
// Internally: f16 MFMA (16x16x32), fp32 accumulation.
// GEMMs: glds width=16 staging, XOR-swizzled LDS (0 bank conflicts measured),
// XCD-aware 1D grids (r10: FETCH 83->31 MB on MODE2).
// MODE2 (r12): 64x64 tiles, no atomics; direct epilogue out = acc + b_proj + x2.
// r13: attn persistent + dynamic work queue.
// r14: MODE2 BK=64 (96->48 iters). PASSED 257.5us.
// r15/r16: CROSS-BLOCK split-KV FAILED twice (nondeterministic heavy rows; race
// never localized). Cross-block merge is banned.
// r17: MODE0 DBUF. PASSED 251.4us. attn back on top at 47.8us = serial time of
// heaviest item (32 tiles x 1.49us).
// r18: IN-BLOCK split-KV. 512-thread blocks, two 4-wave groups split the KV
// range (grp0 [0,half), grp1 [half,qt+1), half=(qt+2)>>1, masked tile in the
// longer... in grp1 except qt=0). Private dbuf Ks/Vs/Ps per group (82KB LDS,
// 1 block/CU, grid 256 = same 512 4-wave streams as r17). Merge is in-block:
// grp1 -> LDS scratch (aliases grp0 Ks/Vs, barrier-protected), grp0 adds,
// normalizes, stores. Deterministic; barrier count uniform (loop bound = half
// for both groups). Serial cap 32->16 tiles. Light stream now descending qt
// (tail items are 1-2 tiles).

typedef __attribute__((ext_vector_type(8))) _Float16 half8;
typedef __attribute__((ext_vector_type(4))) float f32x4;

__device__ inline f32x4 mfma16(half8 a, half8 b, f32x4 c) {
    return __builtin_amdgcn_mfma_f32_16x16x32_f16(a, b, c, 0, 0, 0);
}

__device__ __forceinline__ void gld16(const _Float16* g, _Float16* lds) {
    __builtin_amdgcn_global_load_lds(
        (const __attribute__((address_space(1))) void*)(uintptr_t)g,
        (__attribute__((address_space(3))) void*)(uint32_t)(uintptr_t)lds,
        16, 0, 0);
}

// ---------------- fused prep: LN1 + all three weight repacks ----------------
// blocks [0,4096): ln rows; [4096,5824): qkv repack; [5824,8128): wh; [8128,10432): wp
__global__ __launch_bounds__(256) void prep_kernel(
    const float* __restrict__ x, const float* __restrict__ g, const float* __restrict__ bta,
    _Float16* __restrict__ h1,
    const float* __restrict__ wq, const float* __restrict__ wk, const float* __restrict__ wv,
    _Float16* __restrict__ wqkv,
    const float* __restrict__ w_hidden, _Float16* __restrict__ wh,
    const float* __restrict__ w_proj, _Float16* __restrict__ wp,
    int* __restrict__ ctr) {
    __shared__ float tile[32][33];
    int bid = blockIdx.x;
    int tid = threadIdx.x;
    if (bid == 0 && tid == 0) *ctr = 0;   // work-queue reset for attn_kernel
    if (bid < 4096) {
        int row = bid;
        const float* xr = x + (size_t)row * 768;
        float v[3], s = 0.f, s2 = 0.f;
#pragma unroll
        for (int i = 0; i < 3; i++) { v[i] = xr[tid + i * 256]; s += v[i]; s2 += v[i] * v[i]; }
#pragma unroll
        for (int off = 32; off; off >>= 1) { s += __shfl_down(s, off, 64); s2 += __shfl_down(s2, off, 64); }
        float* red = &tile[0][0];
        int wave = tid >> 6, lane = tid & 63;
        if (lane == 0) { red[wave] = s; red[4 + wave] = s2; }
        __syncthreads();
        if (tid == 0) {
            float ts = red[0] + red[1] + red[2] + red[3];
            float ts2 = red[4] + red[5] + red[6] + red[7];
            float mu = ts * (1.f / 768.f);
            float var = ts2 * (1.f / 768.f) - mu * mu;
            red[0] = mu; red[1] = rsqrtf(var + 1e-5f);
        }
        __syncthreads();
        float mu = red[0], rstd = red[1];
#pragma unroll
        for (int i = 0; i < 3; i++) {
            int c = tid + i * 256;
            h1[(size_t)row * 768 + c] = (_Float16)((v[i] - mu) * rstd * g[c] + bta[c]);
        }
        return;
    }
    int tx = tid & 31, ty = tid >> 5;
    if (bid < 5824) {
        int idx = bid - 4096;
        int y = idx / 24, bx = idx % 24;
        int sel = y / 24, rem = y % 24, h = rem >> 1, dt = rem & 1;
        const float* src = (sel == 0) ? wq : ((sel == 1) ? wk : wv);
        int c0 = bx * 32, d0 = dt * 32;
#pragma unroll
        for (int i = 0; i < 4; i++) {
            int c = ty + i * 8;
            tile[c][tx] = src[((size_t)h * 768 + c0 + c) * 64 + d0 + tx];
        }
        __syncthreads();
#pragma unroll
        for (int i = 0; i < 4; i++) {
            int d = ty + i * 8;
            wqkv[((size_t)(sel * 768 + h * 64 + d0 + d)) * 768 + c0 + tx] = (_Float16)tile[tx][d];
        }
        return;
    }
    const float* w; _Float16* wt; int K, N, idx;
    if (bid < 8128) { idx = bid - 5824; w = w_hidden; wt = wh; K = 768; N = 3072; }
    else            { idx = bid - 8128; w = w_proj;   wt = wp; K = 3072; N = 768; }
    int nb = N / 32;
    int n0 = (idx % nb) * 32, k0 = (idx / nb) * 32;
#pragma unroll
    for (int i = 0; i < 4; i++) {
        int k = ty + i * 8;
        tile[k][tx] = w[(size_t)(k0 + k) * N + n0 + tx];
    }
    __syncthreads();
#pragma unroll
    for (int i = 0; i < 4; i++) {
        int n = ty + i * 8;
        wt[(size_t)(n0 + n) * K + k0 + tx] = (_Float16)tile[tx][n];
    }
}

// x2 = x + attn; h2 = LN(x2)   (x2 is MODE2's residual input)
__global__ __launch_bounds__(256) void addln_kernel(const float* __restrict__ x,
                                                    const float* __restrict__ attn,
                                                    const float* __restrict__ g,
                                                    const float* __restrict__ bta,
                                                    float* __restrict__ x2,
                                                    _Float16* __restrict__ out) {
    int row = blockIdx.x;               // b*2048 + t
    const float* xr = x + (size_t)row * 768;
    const float* ar = attn + (size_t)row * 768;
    int tid = threadIdx.x;
    float v[3], s = 0.f, s2 = 0.f;
#pragma unroll
    for (int i = 0; i < 3; i++) {
        int c = tid + i * 256;
        v[i] = xr[c] + ar[c];
        x2[(size_t)row * 768 + c] = v[i];
        s += v[i]; s2 += v[i] * v[i];
    }
#pragma unroll
    for (int off = 32; off; off >>= 1) { s += __shfl_down(s, off, 64); s2 += __shfl_down(s2, off, 64); }
    __shared__ float red[8];
    int wave = tid >> 6, lane = tid & 63;
    if (lane == 0) { red[wave] = s; red[4 + wave] = s2; }
    __syncthreads();
    if (tid == 0) {
        float ts = red[0] + red[1] + red[2] + red[3];
        float ts2 = red[4] + red[5] + red[6] + red[7];
        float mu = ts * (1.f / 768.f);
        float var = ts2 * (1.f / 768.f) - mu * mu;
        red[0] = mu; red[1] = rsqrtf(var + 1e-5f);
    }
    __syncthreads();
    float mu = red[0], rstd = red[1];
#pragma unroll
    for (int i = 0; i < 3; i++) {
        int c = tid + i * 256;
        out[(size_t)row * 768 + c] = (_Float16)((v[i] - mu) * rstd * g[c] + bta[c]);
    }
}

// ---------------- MFMA GEMM BMxBN tile, BK templated, glds staging ----------------
// BK=32 LDS: row = 4 chunks of 16B, phys chunk = c ^ ((row>>1)&3)  (0 conflicts, r3).
// BK=64 LDS: row = 8 chunks of 16B, phys chunk = c ^ (row&7)  (attn-proven pattern).
// 1D XCD grid: xcd = bid&7; s = bid>>3; m-tile = xcd*MPX + s/NT; n-tile = s%NT.
// MODE 0 (128x128): scatter q(b,h,t,d)[*1/sqrt(768)], k(b,h,t,d), vt(b,h,d,t)
// MODE 1 (128x128): +bias, relu -> f16 out [M][N]
// MODE 2 (64x64):   +bias +resid -> f32 out [M][N], no atomics, KSPLIT=1
template <int MODE, bool DBUF, int BK, int BM, int BN, int NT, int MPX>
__global__ __launch_bounds__(256) void gemm_kernel(
    const _Float16* __restrict__ A, const _Float16* __restrict__ Bt, int N, int K,
    const float* __restrict__ bias, const float* __restrict__ resid,
    float* __restrict__ outF, _Float16* __restrict__ outH,
    _Float16* __restrict__ qb, _Float16* __restrict__ kb, _Float16* __restrict__ vtb) {
    constexpr int NBUF = DBUF ? 2 : 1;
    constexpr int IM = BM / 32, JN = BN / 32;
    __shared__ __align__(16) _Float16 As[NBUF][BM * BK];
    __shared__ __align__(16) _Float16 Bs[NBUF][BN * BK];
    const int tid = threadIdx.x;
    const int wave = tid >> 6, lane = tid & 63;

    const int bid = blockIdx.x;
    const int xcd = bid & 7, s = bid >> 3;
    const int m0 = (xcd * MPX + s / NT) * BM;
    const int n0 = (s % NT) * BN;

    const int wm = (wave >> 1) * (BM / 2), wn = (wave & 1) * (BN / 2);
    const int lr = lane & 15, lq = lane >> 4;
    const int nIter = K / BK;

    auto stage = [&](int k0, int bsel) {
        if constexpr (BK == 32) {
            const int sr = lane >> 2;
            const int sc = (lane & 3) ^ ((lane >> 3) & 3);
#pragma unroll
            for (int t = 0; t < BM / 64; ++t) {
                int row = wave * (BM / 4) + t * 16;
                gld16(&A[(size_t)(m0 + row + sr) * K + k0 + sc * 8], &As[bsel][row * 32]);
            }
#pragma unroll
            for (int t = 0; t < BN / 64; ++t) {
                int row = wave * (BN / 4) + t * 16;
                gld16(&Bt[(size_t)(n0 + row + sr) * K + k0 + sc * 8], &Bs[bsel][row * 32]);
            }
        } else {
            const int sr8 = lane >> 3;                 // row within group of 8
            const int sc8 = (lane & 7) ^ sr8;          // swizzled 16B chunk
#pragma unroll
            for (int t = 0; t < BM / 32; ++t) {
                int row0 = wave * (BM / 4) + t * 8;
                gld16(&A[(size_t)(m0 + row0 + sr8) * K + k0 + sc8 * 8], &As[bsel][row0 * 64]);
            }
#pragma unroll
            for (int t = 0; t < BN / 32; ++t) {
                int row0 = wave * (BN / 4) + t * 8;
                gld16(&Bt[(size_t)(n0 + row0 + sr8) * K + k0 + sc8 * 8], &Bs[bsel][row0 * 64]);
            }
        }
    };

    auto compute = [&](int bsel, f32x4 (&acc)[IM][JN]) {
        if constexpr (BK == 32) {
            half8 af[IM], bf[JN];
            const int cs = (lq ^ ((lr >> 1) & 3)) * 8;
#pragma unroll
            for (int i = 0; i < IM; i++) af[i] = *(const half8*)&As[bsel][(wm + i * 16 + lr) * 32 + cs];
#pragma unroll
            for (int j = 0; j < JN; j++) bf[j] = *(const half8*)&Bs[bsel][(wn + j * 16 + lr) * 32 + cs];
#pragma unroll
            for (int i = 0; i < IM; i++)
#pragma unroll
                for (int j = 0; j < JN; j++)
                    acc[i][j] = mfma16(af[i], bf[j], acc[i][j]);
        } else {
#pragma unroll
            for (int ks = 0; ks < 2; ks++) {
                half8 af[IM], bf[JN];
                const int cs = ((ks * 4 + lq) ^ (lr & 7)) * 8;
#pragma unroll
                for (int i = 0; i < IM; i++) af[i] = *(const half8*)&As[bsel][(wm + i * 16 + lr) * 64 + cs];
#pragma unroll
                for (int j = 0; j < JN; j++) bf[j] = *(const half8*)&Bs[bsel][(wn + j * 16 + lr) * 64 + cs];
#pragma unroll
                for (int i = 0; i < IM; i++)
#pragma unroll
                    for (int j = 0; j < JN; j++)
                        acc[i][j] = mfma16(af[i], bf[j], acc[i][j]);
            }
        }
    };

    f32x4 acc[IM][JN] = {};

    if constexpr (DBUF) {
        stage(0, 0);
        for (int it = 0; it < nIter; ++it) {
            __syncthreads();                 // drains prefetch of tile it
            if (it + 1 < nIter) stage((it + 1) * BK, (it + 1) & 1);
            compute(it & 1, acc);
        }
    } else {
        for (int it = 0; it < nIter; ++it) {
            stage(it * BK, 0);
            __syncthreads();
            compute(0, acc);
            __syncthreads();
        }
    }

    const float qscale = 0.03608439182435161f;  // 1/sqrt(768)
#pragma unroll
    for (int i = 0; i < IM; i++) {
#pragma unroll
        for (int j = 0; j < JN; j++) {
            int n = n0 + wn + j * 16 + lr;
            int mb = m0 + wm + i * 16 + lq * 4;
#pragma unroll
            for (int r = 0; r < 4; r++) {
                int m = mb + r;
                float v = acc[i][j][r];
                if constexpr (MODE == 0) {
                    int b = m >> 11, t = m & 2047;
                    int sel = n / 768, nn = n % 768;
                    int h = nn >> 6, d = nn & 63;
                    size_t bh = (size_t)(b * 12 + h);
                    if (sel == 0)      qb[(bh * 2048 + t) * 64 + d] = (_Float16)(v * qscale);
                    else if (sel == 1) kb[(bh * 2048 + t) * 64 + d] = (_Float16)v;
                    else               vtb[(bh * 64 + d) * 2048 + t] = (_Float16)v;
                } else if constexpr (MODE == 1) {
                    v += bias[n];
                    v = v > 0.f ? v : 0.f;
                    outH[(size_t)m * N + n] = (_Float16)v;
                } else {
                    v += bias[n] + resid[(size_t)m * N + n];
                    outF[(size_t)m * N + n] = v;
                }
            }
        }
    }
}

// ---------------- flash attention (causal), persistent queue + IN-BLOCK split-KV ----
// 768 items: even id -> heavy qt = 31 - (id>>1)/24; odd id -> light qt = 15 - (id>>1)/24
// (both descending); bh = (id>>1) % 24. 512-thread blocks: grp0 (tid<256) computes KV
// tiles [0,half), grp1 [half,qt+1), half=(qt+2)>>1. Each group: private dbuf Ks/Vs/Ps.
// Merge in-block: grp1 raw O/lsum -> LDS scratch (aliases grp0's Ks/Vs; all compute
// finished at that barrier), grp0 adds + normalizes + stores. Barrier count identical
// for all 512 threads (loop bound = half for both groups; shorter group predicated).
__global__ __launch_bounds__(512) void attn_kernel(const _Float16* __restrict__ qb,
                                                   const _Float16* __restrict__ kb,
                                                   const _Float16* __restrict__ vtb,
                                                   float* __restrict__ attn_out,
                                                   int* __restrict__ counter) {
    __shared__ __align__(16) _Float16 Ks[2][2][64 * 64];   // [grp][buf]
    __shared__ __align__(16) _Float16 Vs[2][2][64 * 64];
    __shared__ __align__(16) _Float16 Ps[2][4][16 * 72];   // [grp][wave]
    __shared__ int s_item;
    const int tid = threadIdx.x;
    const int grp = tid >> 8, tid8 = tid & 255;
    const int wave8 = tid8 >> 6, lane = tid & 63;
    const int lr = lane & 15, lq = lane >> 4;
    const int sr = lane >> 3;            // staging row within 8
    const int sc = (lane & 7) ^ sr;      // swizzled chunk
    // Merge scratch aliases grp0's buffers; only touched after the post-loop barrier
    // (all LDS reads done) and re-staged only after the next item's top barrier.
    float* mO = (float*)&Ks[0][0][0];    // 256 threads x 16 floats = 16 KB (Ks grp0 = 16 KB)
    float* mL = (float*)&Vs[0][0][0];    // 256 threads x 4 floats  =  4 KB

    for (;;) {
        __syncthreads();                     // P1: merge reads done; LDS reusable
        if (tid == 0) s_item = atomicAdd(counter, 1);
        __syncthreads();                     // P2: s_item visible
        const int item = s_item;
        if (item >= 768) break;

        const int j = item >> 1;
        const int jq = j / 24;
        const int qt = (item & 1) ? (15 - jq) : (31 - jq);
        const int bh = j - jq * 24;
        const int b = bh / 12, h = bh % 12;
        const int q0 = qt * 64;
        const int half = (qt + 2) >> 1;      // grp0 tile count
        const int n1 = qt + 1 - half;        // grp1 tile count (== half or half-1)
        const int myN = grp ? n1 : half;
        const int myT0 = grp ? half : 0;

        const _Float16* qbase = qb + (size_t)bh * 2048 * 64;
        const _Float16* kbase = kb + (size_t)bh * 2048 * 64;
        const _Float16* vbase = vtb + (size_t)bh * 64 * 2048;

        half8 qf[2];
#pragma unroll
        for (int kd2 = 0; kd2 < 2; kd2++)
            qf[kd2] = *(const half8*)&qbase[(size_t)(q0 + wave8 * 16 + lr) * 64 + kd2 * 32 + lq * 8];

        auto stageKV = [&](int tile, int bsel) {
            int kv0 = tile << 6;
#pragma unroll
            for (int u = 0; u < 2; ++u) {
                int row0 = wave8 * 16 + u * 8;
                gld16(&kbase[(size_t)(kv0 + row0 + sr) * 64 + sc * 8], &Ks[grp][bsel][row0 * 64]);
                gld16(&vbase[(size_t)(row0 + sr) * 2048 + kv0 + sc * 8], &Vs[grp][bsel][row0 * 64]);
            }
        };

        f32x4 O[4] = {};
        float lsum[4] = {0.f, 0.f, 0.f, 0.f};
        if (myN > 0) stageKV(myT0, 0);

        for (int i = 0; i < half; ++i) {
            __syncthreads();                      // drains glds for local tile i
            if (i + 1 < myN) stageKV(myT0 + i + 1, (i + 1) & 1);
            if (i < myN) {
                const int t = myT0 + i;
                const int bs = i & 1, kv0 = t << 6;
                const bool mask = (t == qt);

                f32x4 S[4] = {};
#pragma unroll
                for (int kd2 = 0; kd2 < 2; kd2++) {
#pragma unroll
                    for (int nf = 0; nf < 4; nf++) {
                        half8 bk = *(const half8*)&Ks[grp][bs][(nf * 16 + lr) * 64 +
                                                               (((kd2 * 4 + lq) ^ (lr & 7)) * 8)];
                        S[nf] = mfma16(qf[kd2], bk, S[nf]);
                    }
                }

                const int qi_base = q0 + wave8 * 16 + lq * 4;
#pragma unroll
                for (int r = 0; r < 4; r++) {
                    float a = 0.f;
#pragma unroll
                    for (int nf = 0; nf < 4; nf++) {
                        float p = __expf(S[nf][r]);
                        if (mask) {
                            int kidx = kv0 + nf * 16 + lr;
                            if (kidx > qi_base + r) p = 0.f;
                        }
                        a += p;
                        Ps[grp][wave8][(lq * 4 + r) * 72 + nf * 16 + lr] = (_Float16)p;
                    }
                    lsum[r] += a;
                }

#pragma unroll
                for (int ks = 0; ks < 2; ks++) {
                    half8 ap = *(const half8*)&Ps[grp][wave8][lr * 72 + ks * 32 + lq * 8];
#pragma unroll
                    for (int df = 0; df < 4; df++) {
                        half8 bv = *(const half8*)&Vs[grp][bs][(df * 16 + lr) * 64 +
                                                               (((ks * 4 + lq) ^ (lr & 7)) * 8)];
                        O[df] = mfma16(ap, bv, O[df]);
                    }
                }
            }
        }

        __syncthreads();                     // P3: all compute done; scratch safe
        if (grp == 1) {
#pragma unroll
            for (int df = 0; df < 4; df++)
#pragma unroll
                for (int r = 0; r < 4; r++)
                    mO[(df * 4 + r) * 256 + tid8] = O[df][r];
#pragma unroll
            for (int r = 0; r < 4; r++) mL[r * 256 + tid8] = lsum[r];
        }
        __syncthreads();                     // P4: scratch visible to grp0
        if (grp == 0) {
#pragma unroll
            for (int df = 0; df < 4; df++)
#pragma unroll
                for (int r = 0; r < 4; r++)
                    O[df][r] += mO[(df * 4 + r) * 256 + tid8];
#pragma unroll
            for (int r = 0; r < 4; r++) {
                lsum[r] += mL[r * 256 + tid8];
#pragma unroll
                for (int off = 1; off < 16; off <<= 1) lsum[r] += __shfl_xor(lsum[r], off, 64);
            }
#pragma unroll
            for (int df = 0; df < 4; df++) {
#pragma unroll
                for (int r = 0; r < 4; r++) {
                    int t = q0 + wave8 * 16 + lq * 4 + r;
                    int d = df * 16 + lr;
                    attn_out[((size_t)b * 2048 + t) * 768 + h * 64 + d] = O[df][r] / lsum[r];
                }
            }
        }
    }
}

extern "C" void kernel_launch(void* const* d_in, const int* in_sizes, int n_in,
                              void* d_out, int out_size, void* d_ws, size_t ws_size,
                              hipStream_t stream) {
    (void)in_sizes; (void)n_in; (void)out_size; (void)ws_size;
    const float* x        = (const float*)d_in[0];
    const float* ln1_g    = (const float*)d_in[1];
    const float* ln1_b    = (const float*)d_in[2];
    const float* wq       = (const float*)d_in[3];
    const float* wk       = (const float*)d_in[4];
    const float* wv       = (const float*)d_in[5];
    const float* ln2_g    = (const float*)d_in[6];
    const float* ln2_b    = (const float*)d_in[7];
    const float* w_hidden = (const float*)d_in[8];
    const float* b_hidden = (const float*)d_in[9];
    const float* w_proj   = (const float*)d_in[10];
    const float* b_proj   = (const float*)d_in[11];
    float* out = (float*)d_out;

    uint8_t* p = (uint8_t*)d_ws;
    _Float16* h1   = (_Float16*)p; p += 4096ull * 768 * 2;
    _Float16* wqkv = (_Float16*)p; p += 2304ull * 768 * 2;
    _Float16* wh   = (_Float16*)p; p += 3072ull * 768 * 2;
    _Float16* wp   = (_Float16*)p; p += 768ull * 3072 * 2;
    _Float16* qb   = (_Float16*)p; p += 24ull * 2048 * 64 * 2;
    _Float16* kb   = (_Float16*)p; p += 24ull * 2048 * 64 * 2;
    _Float16* vtb  = (_Float16*)p; p += 24ull * 2048 * 64 * 2;
    float*    attn = (float*)p;    p += 4096ull * 768 * 4;
    float*    x2   = (float*)p;    p += 4096ull * 768 * 4;
    _Float16* h2   = (_Float16*)p; p += 4096ull * 768 * 2;
    _Float16* hid  = (_Float16*)p; p += 4096ull * 3072 * 2;
    int*      ctr  = (int*)p;      p += 256;

    prep_kernel<<<10432, 256, 0, stream>>>(x, ln1_g, ln1_b, h1,
        wq, wk, wv, wqkv, w_hidden, wh, w_proj, wp, ctr);
    // MODE0: 32m x 18n (128x128), BK=32, DBUF (r17), XCD 1D grid 576
    gemm_kernel<0, true, 32, 128, 128, 18, 4><<<576, 256, 0, stream>>>(h1, wqkv, 2304, 768,
        nullptr, nullptr, nullptr, nullptr, qb, kb, vtb);
    // r18: 256 persistent 512-thread blocks (1/CU by LDS), in-block split-KV
    attn_kernel<<<256, 512, 0, stream>>>(qb, kb, vtb, attn, ctr);
    addln_kernel<<<4096, 256, 0, stream>>>(x, attn, ln2_g, ln2_b, x2, h2);
    // MODE1: 32m x 24n (128x128), BK=32, XCD 1D grid 768
    gemm_kernel<1, true, 32, 128, 128, 24, 4><<<768, 256, 0, stream>>>(h2, wh, 3072, 768,
        b_hidden, nullptr, nullptr, hid, nullptr, nullptr, nullptr);
    // MODE2: 64m x 12n (64x64), BK=64 (r14: 96->48 iters), XCD 1D grid 768
    gemm_kernel<2, true, 64, 64, 64, 12, 8><<<768, 256, 0, stream>>>(hid, wp, 768, 3072,
        b_proj, x2, out, nullptr, nullptr, nullptr, nullptr);
}

// Round 7
// 248.117 us; speedup vs baseline: 1.0235x; 1.0235x over previous
//
#include <hip/hip_runtime.h>
#include <stdint.h>

// B=2, T=2048, C=768, H=12, D=64. All inputs fp32; output fp32.
// Internally: f16 MFMA (16x16x32), fp32 accumulation.
// GEMMs: glds width=16 staging, XOR-swizzled LDS (0 bank conflicts measured),
// XCD-aware 1D grids (r10: FETCH 83->31 MB on MODE2).
// MODE2 (r12): 64x64 tiles, no atomics; direct epilogue out = acc + b_proj + x2.
// r13: attn persistent + dynamic work queue.
// r14: MODE2 BK=64 (96->48 iters). PASSED 257.5us.
// r15/r16: CROSS-BLOCK split-KV FAILED twice (nondeterministic; banned).
// r17: MODE0 DBUF. PASSED 251.4us; attn 47.8us = heavy-item serial floor.
// r18: in-block split-KV REGRESSED (51.8us): 84KB LDS -> 1 block/CU and the
// two KV-groups share barriers -> coupled stalls, no cross-block overlap.
// Heavy-item splitting abandoned (0-for-3).
// r19: revert attn to r17 structure; HALVE barrier count: stage 2-tile
// super-tiles (4 LDS bufs = 2-deep dbuf x 2 subs, 73KB -> still 2 blocks/CU),
// one __syncthreads per PAIR of KV tiles. Per-tile compute body unchanged.
// Light stream descending qt (r18 decode, passed).

typedef __attribute__((ext_vector_type(8))) _Float16 half8;
typedef __attribute__((ext_vector_type(4))) float f32x4;

__device__ inline f32x4 mfma16(half8 a, half8 b, f32x4 c) {
    return __builtin_amdgcn_mfma_f32_16x16x32_f16(a, b, c, 0, 0, 0);
}

__device__ __forceinline__ void gld16(const _Float16* g, _Float16* lds) {
    __builtin_amdgcn_global_load_lds(
        (const __attribute__((address_space(1))) void*)(uintptr_t)g,
        (__attribute__((address_space(3))) void*)(uint32_t)(uintptr_t)lds,
        16, 0, 0);
}

// ---------------- fused prep: LN1 + all three weight repacks ----------------
// blocks [0,4096): ln rows; [4096,5824): qkv repack; [5824,8128): wh; [8128,10432): wp
__global__ __launch_bounds__(256) void prep_kernel(
    const float* __restrict__ x, const float* __restrict__ g, const float* __restrict__ bta,
    _Float16* __restrict__ h1,
    const float* __restrict__ wq, const float* __restrict__ wk, const float* __restrict__ wv,
    _Float16* __restrict__ wqkv,
    const float* __restrict__ w_hidden, _Float16* __restrict__ wh,
    const float* __restrict__ w_proj, _Float16* __restrict__ wp,
    int* __restrict__ ctr) {
    __shared__ float tile[32][33];
    int bid = blockIdx.x;
    int tid = threadIdx.x;
    if (bid == 0 && tid == 0) *ctr = 0;   // work-queue reset for attn_kernel
    if (bid < 4096) {
        int row = bid;
        const float* xr = x + (size_t)row * 768;
        float v[3], s = 0.f, s2 = 0.f;
#pragma unroll
        for (int i = 0; i < 3; i++) { v[i] = xr[tid + i * 256]; s += v[i]; s2 += v[i] * v[i]; }
#pragma unroll
        for (int off = 32; off; off >>= 1) { s += __shfl_down(s, off, 64); s2 += __shfl_down(s2, off, 64); }
        float* red = &tile[0][0];
        int wave = tid >> 6, lane = tid & 63;
        if (lane == 0) { red[wave] = s; red[4 + wave] = s2; }
        __syncthreads();
        if (tid == 0) {
            float ts = red[0] + red[1] + red[2] + red[3];
            float ts2 = red[4] + red[5] + red[6] + red[7];
            float mu = ts * (1.f / 768.f);
            float var = ts2 * (1.f / 768.f) - mu * mu;
            red[0] = mu; red[1] = rsqrtf(var + 1e-5f);
        }
        __syncthreads();
        float mu = red[0], rstd = red[1];
#pragma unroll
        for (int i = 0; i < 3; i++) {
            int c = tid + i * 256;
            h1[(size_t)row * 768 + c] = (_Float16)((v[i] - mu) * rstd * g[c] + bta[c]);
        }
        return;
    }
    int tx = tid & 31, ty = tid >> 5;
    if (bid < 5824) {
        int idx = bid - 4096;
        int y = idx / 24, bx = idx % 24;
        int sel = y / 24, rem = y % 24, h = rem >> 1, dt = rem & 1;
        const float* src = (sel == 0) ? wq : ((sel == 1) ? wk : wv);
        int c0 = bx * 32, d0 = dt * 32;
#pragma unroll
        for (int i = 0; i < 4; i++) {
            int c = ty + i * 8;
            tile[c][tx] = src[((size_t)h * 768 + c0 + c) * 64 + d0 + tx];
        }
        __syncthreads();
#pragma unroll
        for (int i = 0; i < 4; i++) {
            int d = ty + i * 8;
            wqkv[((size_t)(sel * 768 + h * 64 + d0 + d)) * 768 + c0 + tx] = (_Float16)tile[tx][d];
        }
        return;
    }
    const float* w; _Float16* wt; int K, N, idx;
    if (bid < 8128) { idx = bid - 5824; w = w_hidden; wt = wh; K = 768; N = 3072; }
    else            { idx = bid - 8128; w = w_proj;   wt = wp; K = 3072; N = 768; }
    int nb = N / 32;
    int n0 = (idx % nb) * 32, k0 = (idx / nb) * 32;
#pragma unroll
    for (int i = 0; i < 4; i++) {
        int k = ty + i * 8;
        tile[k][tx] = w[(size_t)(k0 + k) * N + n0 + tx];
    }
    __syncthreads();
#pragma unroll
    for (int i = 0; i < 4; i++) {
        int n = ty + i * 8;
        wt[(size_t)(n0 + n) * K + k0 + tx] = (_Float16)tile[tx][n];
    }
}

// x2 = x + attn; h2 = LN(x2)   (x2 is MODE2's residual input)
__global__ __launch_bounds__(256) void addln_kernel(const float* __restrict__ x,
                                                    const float* __restrict__ attn,
                                                    const float* __restrict__ g,
                                                    const float* __restrict__ bta,
                                                    float* __restrict__ x2,
                                                    _Float16* __restrict__ out) {
    int row = blockIdx.x;               // b*2048 + t
    const float* xr = x + (size_t)row * 768;
    const float* ar = attn + (size_t)row * 768;
    int tid = threadIdx.x;
    float v[3], s = 0.f, s2 = 0.f;
#pragma unroll
    for (int i = 0; i < 3; i++) {
        int c = tid + i * 256;
        v[i] = xr[c] + ar[c];
        x2[(size_t)row * 768 + c] = v[i];
        s += v[i]; s2 += v[i] * v[i];
    }
#pragma unroll
    for (int off = 32; off; off >>= 1) { s += __shfl_down(s, off, 64); s2 += __shfl_down(s2, off, 64); }
    __shared__ float red[8];
    int wave = tid >> 6, lane = tid & 63;
    if (lane == 0) { red[wave] = s; red[4 + wave] = s2; }
    __syncthreads();
    if (tid == 0) {
        float ts = red[0] + red[1] + red[2] + red[3];
        float ts2 = red[4] + red[5] + red[6] + red[7];
        float mu = ts * (1.f / 768.f);
        float var = ts2 * (1.f / 768.f) - mu * mu;
        red[0] = mu; red[1] = rsqrtf(var + 1e-5f);
    }
    __syncthreads();
    float mu = red[0], rstd = red[1];
#pragma unroll
    for (int i = 0; i < 3; i++) {
        int c = tid + i * 256;
        out[(size_t)row * 768 + c] = (_Float16)((v[i] - mu) * rstd * g[c] + bta[c]);
    }
}

// ---------------- MFMA GEMM BMxBN tile, BK templated, glds staging ----------------
// BK=32 LDS: row = 4 chunks of 16B, phys chunk = c ^ ((row>>1)&3)  (0 conflicts, r3).
// BK=64 LDS: row = 8 chunks of 16B, phys chunk = c ^ (row&7)  (attn-proven pattern).
// 1D XCD grid: xcd = bid&7; s = bid>>3; m-tile = xcd*MPX + s/NT; n-tile = s%NT.
// MODE 0 (128x128): scatter q(b,h,t,d)[*1/sqrt(768)], k(b,h,t,d), vt(b,h,d,t)
// MODE 1 (128x128): +bias, relu -> f16 out [M][N]
// MODE 2 (64x64):   +bias +resid -> f32 out [M][N], no atomics, KSPLIT=1
template <int MODE, bool DBUF, int BK, int BM, int BN, int NT, int MPX>
__global__ __launch_bounds__(256) void gemm_kernel(
    const _Float16* __restrict__ A, const _Float16* __restrict__ Bt, int N, int K,
    const float* __restrict__ bias, const float* __restrict__ resid,
    float* __restrict__ outF, _Float16* __restrict__ outH,
    _Float16* __restrict__ qb, _Float16* __restrict__ kb, _Float16* __restrict__ vtb) {
    constexpr int NBUF = DBUF ? 2 : 1;
    constexpr int IM = BM / 32, JN = BN / 32;
    __shared__ __align__(16) _Float16 As[NBUF][BM * BK];
    __shared__ __align__(16) _Float16 Bs[NBUF][BN * BK];
    const int tid = threadIdx.x;
    const int wave = tid >> 6, lane = tid & 63;

    const int bid = blockIdx.x;
    const int xcd = bid & 7, s = bid >> 3;
    const int m0 = (xcd * MPX + s / NT) * BM;
    const int n0 = (s % NT) * BN;

    const int wm = (wave >> 1) * (BM / 2), wn = (wave & 1) * (BN / 2);
    const int lr = lane & 15, lq = lane >> 4;
    const int nIter = K / BK;

    auto stage = [&](int k0, int bsel) {
        if constexpr (BK == 32) {
            const int sr = lane >> 2;
            const int sc = (lane & 3) ^ ((lane >> 3) & 3);
#pragma unroll
            for (int t = 0; t < BM / 64; ++t) {
                int row = wave * (BM / 4) + t * 16;
                gld16(&A[(size_t)(m0 + row + sr) * K + k0 + sc * 8], &As[bsel][row * 32]);
            }
#pragma unroll
            for (int t = 0; t < BN / 64; ++t) {
                int row = wave * (BN / 4) + t * 16;
                gld16(&Bt[(size_t)(n0 + row + sr) * K + k0 + sc * 8], &Bs[bsel][row * 32]);
            }
        } else {
            const int sr8 = lane >> 3;                 // row within group of 8
            const int sc8 = (lane & 7) ^ sr8;          // swizzled 16B chunk
#pragma unroll
            for (int t = 0; t < BM / 32; ++t) {
                int row0 = wave * (BM / 4) + t * 8;
                gld16(&A[(size_t)(m0 + row0 + sr8) * K + k0 + sc8 * 8], &As[bsel][row0 * 64]);
            }
#pragma unroll
            for (int t = 0; t < BN / 32; ++t) {
                int row0 = wave * (BN / 4) + t * 8;
                gld16(&Bt[(size_t)(n0 + row0 + sr8) * K + k0 + sc8 * 8], &Bs[bsel][row0 * 64]);
            }
        }
    };

    auto compute = [&](int bsel, f32x4 (&acc)[IM][JN]) {
        if constexpr (BK == 32) {
            half8 af[IM], bf[JN];
            const int cs = (lq ^ ((lr >> 1) & 3)) * 8;
#pragma unroll
            for (int i = 0; i < IM; i++) af[i] = *(const half8*)&As[bsel][(wm + i * 16 + lr) * 32 + cs];
#pragma unroll
            for (int j = 0; j < JN; j++) bf[j] = *(const half8*)&Bs[bsel][(wn + j * 16 + lr) * 32 + cs];
#pragma unroll
            for (int i = 0; i < IM; i++)
#pragma unroll
                for (int j = 0; j < JN; j++)
                    acc[i][j] = mfma16(af[i], bf[j], acc[i][j]);
        } else {
#pragma unroll
            for (int ks = 0; ks < 2; ks++) {
                half8 af[IM], bf[JN];
                const int cs = ((ks * 4 + lq) ^ (lr & 7)) * 8;
#pragma unroll
                for (int i = 0; i < IM; i++) af[i] = *(const half8*)&As[bsel][(wm + i * 16 + lr) * 64 + cs];
#pragma unroll
                for (int j = 0; j < JN; j++) bf[j] = *(const half8*)&Bs[bsel][(wn + j * 16 + lr) * 64 + cs];
#pragma unroll
                for (int i = 0; i < IM; i++)
#pragma unroll
                    for (int j = 0; j < JN; j++)
                        acc[i][j] = mfma16(af[i], bf[j], acc[i][j]);
            }
        }
    };

    f32x4 acc[IM][JN] = {};

    if constexpr (DBUF) {
        stage(0, 0);
        for (int it = 0; it < nIter; ++it) {
            __syncthreads();                 // drains prefetch of tile it
            if (it + 1 < nIter) stage((it + 1) * BK, (it + 1) & 1);
            compute(it & 1, acc);
        }
    } else {
        for (int it = 0; it < nIter; ++it) {
            stage(it * BK, 0);
            __syncthreads();
            compute(0, acc);
            __syncthreads();
        }
    }

    const float qscale = 0.03608439182435161f;  // 1/sqrt(768)
#pragma unroll
    for (int i = 0; i < IM; i++) {
#pragma unroll
        for (int j = 0; j < JN; j++) {
            int n = n0 + wn + j * 16 + lr;
            int mb = m0 + wm + i * 16 + lq * 4;
#pragma unroll
            for (int r = 0; r < 4; r++) {
                int m = mb + r;
                float v = acc[i][j][r];
                if constexpr (MODE == 0) {
                    int b = m >> 11, t = m & 2047;
                    int sel = n / 768, nn = n % 768;
                    int h = nn >> 6, d = nn & 63;
                    size_t bh = (size_t)(b * 12 + h);
                    if (sel == 0)      qb[(bh * 2048 + t) * 64 + d] = (_Float16)(v * qscale);
                    else if (sel == 1) kb[(bh * 2048 + t) * 64 + d] = (_Float16)v;
                    else               vtb[(bh * 64 + d) * 2048 + t] = (_Float16)v;
                } else if constexpr (MODE == 1) {
                    v += bias[n];
                    v = v > 0.f ? v : 0.f;
                    outH[(size_t)m * N + n] = (_Float16)v;
                } else {
                    v += bias[n] + resid[(size_t)m * N + n];
                    outF[(size_t)m * N + n] = v;
                }
            }
        }
    }
}

// ---------------- flash attention (causal), persistent queue, paired KV tiles ----
// Items: id even -> heavy qt = 31 - (id>>1)/24; id odd -> light qt = 15 - (id>>1)/24
// (both descending); bh = (id>>1) % 24. 768 items, 512 blocks (256 thr, 2/CU).
// r19: KV tiles processed in PAIRS per barrier. LDS = 2-deep dbuf x 2 sub-tiles
// (Ks/Vs [buf][sub]), 73KB total -> 2 blocks/CU (same resident as r17). One
// __syncthreads per super-tile (pair) instead of per tile: 32 -> 16 barriers
// on the heavy item. Per-tile compute body identical to r17 (proven).
__global__ __launch_bounds__(256) void attn_kernel(const _Float16* __restrict__ qb,
                                                   const _Float16* __restrict__ kb,
                                                   const _Float16* __restrict__ vtb,
                                                   float* __restrict__ attn_out,
                                                   int* __restrict__ counter) {
    __shared__ __align__(16) _Float16 Ks[2][2][64 * 64];   // [buf][sub]
    __shared__ __align__(16) _Float16 Vs[2][2][64 * 64];
    __shared__ __align__(16) _Float16 Ps[4][16 * 72];
    __shared__ int s_item;
    const int tid = threadIdx.x, wave = tid >> 6, lane = tid & 63;
    const int lr = lane & 15, lq = lane >> 4;
    const int sr = lane >> 3;            // staging row within 8
    const int sc = (lane & 7) ^ sr;      // swizzled chunk

    for (;;) {
        __syncthreads();                     // all waves done with LDS + s_item
        if (tid == 0) s_item = atomicAdd(counter, 1);
        __syncthreads();
        const int item = s_item;
        if (item >= 768) break;

        const int j = item >> 1;
        const int jq = j / 24;
        const int qt = (item & 1) ? (15 - jq) : (31 - jq);
        const int bh = j - jq * 24;
        const int b = bh / 12, h = bh % 12;
        const int q0 = qt * 64;

        const _Float16* qbase = qb + (size_t)bh * 2048 * 64;
        const _Float16* kbase = kb + (size_t)bh * 2048 * 64;
        const _Float16* vbase = vtb + (size_t)bh * 64 * 2048;

        half8 qf[2];
#pragma unroll
        for (int kd2 = 0; kd2 < 2; kd2++)
            qf[kd2] = *(const half8*)&qbase[(size_t)(q0 + wave * 16 + lr) * 64 + kd2 * 32 + lq * 8];

        auto stageKV = [&](int tile, int bsel, int sub) {
            int kv0 = tile << 6;
#pragma unroll
            for (int u = 0; u < 2; ++u) {
                int row0 = wave * 16 + u * 8;
                gld16(&kbase[(size_t)(kv0 + row0 + sr) * 64 + sc * 8], &Ks[bsel][sub][row0 * 64]);
                gld16(&vbase[(size_t)(row0 + sr) * 2048 + kv0 + sc * 8], &Vs[bsel][sub][row0 * 64]);
            }
        };

        f32x4 O[4] = {};
        float lsum[4] = {0.f, 0.f, 0.f, 0.f};
        const int nT = qt + 1;
        const int nS = (nT + 1) >> 1;        // super-tiles (pairs)

        // per-tile compute body — identical math to r17
        auto computeTile = [&](int t, int bs, int sub) {
            const int kv0 = t << 6;
            const bool mask = (t == qt);

            f32x4 S[4] = {};
#pragma unroll
            for (int kd2 = 0; kd2 < 2; kd2++) {
#pragma unroll
                for (int nf = 0; nf < 4; nf++) {
                    half8 bk = *(const half8*)&Ks[bs][sub][(nf * 16 + lr) * 64 +
                                                           (((kd2 * 4 + lq) ^ (lr & 7)) * 8)];
                    S[nf] = mfma16(qf[kd2], bk, S[nf]);
                }
            }

            const int qi_base = q0 + wave * 16 + lq * 4;
#pragma unroll
            for (int r = 0; r < 4; r++) {
                float a = 0.f;
#pragma unroll
                for (int nf = 0; nf < 4; nf++) {
                    float p = __expf(S[nf][r]);
                    if (mask) {
                        int kidx = kv0 + nf * 16 + lr;
                        if (kidx > qi_base + r) p = 0.f;
                    }
                    a += p;
                    Ps[wave][(lq * 4 + r) * 72 + nf * 16 + lr] = (_Float16)p;
                }
                lsum[r] += a;
            }

#pragma unroll
            for (int ks = 0; ks < 2; ks++) {
                half8 ap = *(const half8*)&Ps[wave][lr * 72 + ks * 32 + lq * 8];
#pragma unroll
                for (int df = 0; df < 4; df++) {
                    half8 bv = *(const half8*)&Vs[bs][sub][(df * 16 + lr) * 64 +
                                                           (((ks * 4 + lq) ^ (lr & 7)) * 8)];
                    O[df] = mfma16(ap, bv, O[df]);
                }
            }
        };

        // prologue: stage super-tile 0 (tiles 0, 1 if present)
        stageKV(0, 0, 0);
        if (1 < nT) stageKV(1, 0, 1);

        for (int sIdx = 0; sIdx < nS; ++sIdx) {
            __syncthreads();                 // drains glds for super-tile sIdx
            const int nb = (sIdx + 1) * 2;   // first tile of next super-tile
            if (nb < nT) {
                stageKV(nb, (sIdx + 1) & 1, 0);
                if (nb + 1 < nT) stageKV(nb + 1, (sIdx + 1) & 1, 1);
            }
            const int bs = sIdx & 1;
            computeTile(2 * sIdx, bs, 0);
            if (2 * sIdx + 1 < nT) computeTile(2 * sIdx + 1, bs, 1);
        }

#pragma unroll
        for (int r = 0; r < 4; r++) {
#pragma unroll
            for (int off = 1; off < 16; off <<= 1) lsum[r] += __shfl_xor(lsum[r], off, 64);
        }

#pragma unroll
        for (int df = 0; df < 4; df++) {
#pragma unroll
            for (int r = 0; r < 4; r++) {
                int t = q0 + wave * 16 + lq * 4 + r;
                int d = df * 16 + lr;
                attn_out[((size_t)b * 2048 + t) * 768 + h * 64 + d] = O[df][r] / lsum[r];
            }
        }
    }
}

extern "C" void kernel_launch(void* const* d_in, const int* in_sizes, int n_in,
                              void* d_out, int out_size, void* d_ws, size_t ws_size,
                              hipStream_t stream) {
    (void)in_sizes; (void)n_in; (void)out_size; (void)ws_size;
    const float* x        = (const float*)d_in[0];
    const float* ln1_g    = (const float*)d_in[1];
    const float* ln1_b    = (const float*)d_in[2];
    const float* wq       = (const float*)d_in[3];
    const float* wk       = (const float*)d_in[4];
    const float* wv       = (const float*)d_in[5];
    const float* ln2_g    = (const float*)d_in[6];
    const float* ln2_b    = (const float*)d_in[7];
    const float* w_hidden = (const float*)d_in[8];
    const float* b_hidden = (const float*)d_in[9];
    const float* w_proj   = (const float*)d_in[10];
    const float* b_proj   = (const float*)d_in[11];
    float* out = (float*)d_out;

    uint8_t* p = (uint8_t*)d_ws;
    _Float16* h1   = (_Float16*)p; p += 4096ull * 768 * 2;
    _Float16* wqkv = (_Float16*)p; p += 2304ull * 768 * 2;
    _Float16* wh   = (_Float16*)p; p += 3072ull * 768 * 2;
    _Float16* wp   = (_Float16*)p; p += 768ull * 3072 * 2;
    _Float16* qb   = (_Float16*)p; p += 24ull * 2048 * 64 * 2;
    _Float16* kb   = (_Float16*)p; p += 24ull * 2048 * 64 * 2;
    _Float16* vtb  = (_Float16*)p; p += 24ull * 2048 * 64 * 2;
    float*    attn = (float*)p;    p += 4096ull * 768 * 4;
    float*    x2   = (float*)p;    p += 4096ull * 768 * 4;
    _Float16* h2   = (_Float16*)p; p += 4096ull * 768 * 2;
    _Float16* hid  = (_Float16*)p; p += 4096ull * 3072 * 2;
    int*      ctr  = (int*)p;      p += 256;

    prep_kernel<<<10432, 256, 0, stream>>>(x, ln1_g, ln1_b, h1,
        wq, wk, wv, wqkv, w_hidden, wh, w_proj, wp, ctr);
    // MODE0: 32m x 18n (128x128), BK=32, DBUF (r17), XCD 1D grid 576
    gemm_kernel<0, true, 32, 128, 128, 18, 4><<<576, 256, 0, stream>>>(h1, wqkv, 2304, 768,
        nullptr, nullptr, nullptr, nullptr, qb, kb, vtb);
    // r19: 512 persistent 256-thread blocks (2/CU), paired KV tiles per barrier
    attn_kernel<<<512, 256, 0, stream>>>(qb, kb, vtb, attn, ctr);
    addln_kernel<<<4096, 256, 0, stream>>>(x, attn, ln2_g, ln2_b, x2, h2);
    // MODE1: 32m x 24n (128x128), BK=32, XCD 1D grid 768
    gemm_kernel<1, true, 32, 128, 128, 24, 4><<<768, 256, 0, stream>>>(h2, wh, 3072, 768,
        b_hidden, nullptr, nullptr, hid, nullptr, nullptr, nullptr);
    // MODE2: 64m x 12n (64x64), BK=64 (r14: 96->48 iters), XCD 1D grid 768
    gemm_kernel<2, true, 64, 64, 64, 12, 8><<<768, 256, 0, stream>>>(hid, wp, 768, 3072,
        b_proj, x2, out, nullptr, nullptr, nullptr, nullptr);
}

// Round 8
// 247.559 us; speedup vs baseline: 1.0258x; 1.0023x over previous
//
#include <hip/hip_runtime.h>
#include <stdint.h>

// B=2, T=2048, C=768, H=12, D=64. All inputs fp32; output fp32.
// Internally: f16 MFMA (16x16x32), fp32 accumulation.
// GEMMs: glds width=16 staging, XOR-swizzled LDS (0 bank conflicts measured),
// XCD-aware 1D grids (r10: FETCH 83->31 MB on MODE2).
// MODE2 (r12): 64x64 tiles, no atomics; direct epilogue out = acc + b_proj + x2.
// r13: attn persistent + dynamic work queue.
// r14: MODE2 BK=64 (96->48 iters). PASSED 257.5us.
// r15/r16: CROSS-BLOCK split-KV FAILED twice (nondeterministic; banned).
// r17: MODE0 DBUF. PASSED 251.4us; attn 47.8us = heavy-item serial floor.
// r18: in-block split-KV REGRESSED (coupled barriers, 1 block/CU).
// r19: paired KV tiles (barrier halving) — attn FLAT (~50us) => in-chain
// latency, not barrier count. Total 248.1 (light-desc ordering helped).
// r20: ELIMINATE Ps LDS round-trip. Swapped QK^T: S = mfma(K,Q) puts lane's
// P at q=lane&15, k=nf*16+lq*4+r — exactly the A-frag of 16x16x16 MFMA, so
// PV consumes P in-register (no LDS transpose, no shuffles). PV = 16 K=16
// MFMAs; V read as ds_read_b64 (chunk (2nf+(lq>>1))^(lr&7), indep of S).
// lsum = 1 scalar/lane (q=lr), xor16+xor32 reduce + 4 shfl redistribute.
// LDS 75->33KB; grid 768 = 3 blocks/CU. Single-tile dbuf loop (r17-proven).

typedef __attribute__((ext_vector_type(8))) _Float16 half8;
typedef __attribute__((ext_vector_type(4))) _Float16 half4;
typedef __attribute__((ext_vector_type(4))) float f32x4;

__device__ inline f32x4 mfma16(half8 a, half8 b, f32x4 c) {
    return __builtin_amdgcn_mfma_f32_16x16x32_f16(a, b, c, 0, 0, 0);
}
__device__ inline f32x4 mfma16k16(half4 a, half4 b, f32x4 c) {
    return __builtin_amdgcn_mfma_f32_16x16x16f16(a, b, c, 0, 0, 0);
}

__device__ __forceinline__ void gld16(const _Float16* g, _Float16* lds) {
    __builtin_amdgcn_global_load_lds(
        (const __attribute__((address_space(1))) void*)(uintptr_t)g,
        (__attribute__((address_space(3))) void*)(uint32_t)(uintptr_t)lds,
        16, 0, 0);
}

// ---------------- fused prep: LN1 + all three weight repacks ----------------
// blocks [0,4096): ln rows; [4096,5824): qkv repack; [5824,8128): wh; [8128,10432): wp
__global__ __launch_bounds__(256) void prep_kernel(
    const float* __restrict__ x, const float* __restrict__ g, const float* __restrict__ bta,
    _Float16* __restrict__ h1,
    const float* __restrict__ wq, const float* __restrict__ wk, const float* __restrict__ wv,
    _Float16* __restrict__ wqkv,
    const float* __restrict__ w_hidden, _Float16* __restrict__ wh,
    const float* __restrict__ w_proj, _Float16* __restrict__ wp,
    int* __restrict__ ctr) {
    __shared__ float tile[32][33];
    int bid = blockIdx.x;
    int tid = threadIdx.x;
    if (bid == 0 && tid == 0) *ctr = 0;   // work-queue reset for attn_kernel
    if (bid < 4096) {
        int row = bid;
        const float* xr = x + (size_t)row * 768;
        float v[3], s = 0.f, s2 = 0.f;
#pragma unroll
        for (int i = 0; i < 3; i++) { v[i] = xr[tid + i * 256]; s += v[i]; s2 += v[i] * v[i]; }
#pragma unroll
        for (int off = 32; off; off >>= 1) { s += __shfl_down(s, off, 64); s2 += __shfl_down(s2, off, 64); }
        float* red = &tile[0][0];
        int wave = tid >> 6, lane = tid & 63;
        if (lane == 0) { red[wave] = s; red[4 + wave] = s2; }
        __syncthreads();
        if (tid == 0) {
            float ts = red[0] + red[1] + red[2] + red[3];
            float ts2 = red[4] + red[5] + red[6] + red[7];
            float mu = ts * (1.f / 768.f);
            float var = ts2 * (1.f / 768.f) - mu * mu;
            red[0] = mu; red[1] = rsqrtf(var + 1e-5f);
        }
        __syncthreads();
        float mu = red[0], rstd = red[1];
#pragma unroll
        for (int i = 0; i < 3; i++) {
            int c = tid + i * 256;
            h1[(size_t)row * 768 + c] = (_Float16)((v[i] - mu) * rstd * g[c] + bta[c]);
        }
        return;
    }
    int tx = tid & 31, ty = tid >> 5;
    if (bid < 5824) {
        int idx = bid - 4096;
        int y = idx / 24, bx = idx % 24;
        int sel = y / 24, rem = y % 24, h = rem >> 1, dt = rem & 1;
        const float* src = (sel == 0) ? wq : ((sel == 1) ? wk : wv);
        int c0 = bx * 32, d0 = dt * 32;
#pragma unroll
        for (int i = 0; i < 4; i++) {
            int c = ty + i * 8;
            tile[c][tx] = src[((size_t)h * 768 + c0 + c) * 64 + d0 + tx];
        }
        __syncthreads();
#pragma unroll
        for (int i = 0; i < 4; i++) {
            int d = ty + i * 8;
            wqkv[((size_t)(sel * 768 + h * 64 + d0 + d)) * 768 + c0 + tx] = (_Float16)tile[tx][d];
        }
        return;
    }
    const float* w; _Float16* wt; int K, N, idx;
    if (bid < 8128) { idx = bid - 5824; w = w_hidden; wt = wh; K = 768; N = 3072; }
    else            { idx = bid - 8128; w = w_proj;   wt = wp; K = 3072; N = 768; }
    int nb = N / 32;
    int n0 = (idx % nb) * 32, k0 = (idx / nb) * 32;
#pragma unroll
    for (int i = 0; i < 4; i++) {
        int k = ty + i * 8;
        tile[k][tx] = w[(size_t)(k0 + k) * N + n0 + tx];
    }
    __syncthreads();
#pragma unroll
    for (int i = 0; i < 4; i++) {
        int n = ty + i * 8;
        wt[(size_t)(n0 + n) * K + k0 + tx] = (_Float16)tile[tx][n];
    }
}

// x2 = x + attn; h2 = LN(x2)   (x2 is MODE2's residual input)
__global__ __launch_bounds__(256) void addln_kernel(const float* __restrict__ x,
                                                    const float* __restrict__ attn,
                                                    const float* __restrict__ g,
                                                    const float* __restrict__ bta,
                                                    float* __restrict__ x2,
                                                    _Float16* __restrict__ out) {
    int row = blockIdx.x;               // b*2048 + t
    const float* xr = x + (size_t)row * 768;
    const float* ar = attn + (size_t)row * 768;
    int tid = threadIdx.x;
    float v[3], s = 0.f, s2 = 0.f;
#pragma unroll
    for (int i = 0; i < 3; i++) {
        int c = tid + i * 256;
        v[i] = xr[c] + ar[c];
        x2[(size_t)row * 768 + c] = v[i];
        s += v[i]; s2 += v[i] * v[i];
    }
#pragma unroll
    for (int off = 32; off; off >>= 1) { s += __shfl_down(s, off, 64); s2 += __shfl_down(s2, off, 64); }
    __shared__ float red[8];
    int wave = tid >> 6, lane = tid & 63;
    if (lane == 0) { red[wave] = s; red[4 + wave] = s2; }
    __syncthreads();
    if (tid == 0) {
        float ts = red[0] + red[1] + red[2] + red[3];
        float ts2 = red[4] + red[5] + red[6] + red[7];
        float mu = ts * (1.f / 768.f);
        float var = ts2 * (1.f / 768.f) - mu * mu;
        red[0] = mu; red[1] = rsqrtf(var + 1e-5f);
    }
    __syncthreads();
    float mu = red[0], rstd = red[1];
#pragma unroll
    for (int i = 0; i < 3; i++) {
        int c = tid + i * 256;
        out[(size_t)row * 768 + c] = (_Float16)((v[i] - mu) * rstd * g[c] + bta[c]);
    }
}

// ---------------- MFMA GEMM BMxBN tile, BK templated, glds staging ----------------
// BK=32 LDS: row = 4 chunks of 16B, phys chunk = c ^ ((row>>1)&3)  (0 conflicts, r3).
// BK=64 LDS: row = 8 chunks of 16B, phys chunk = c ^ (row&7)  (attn-proven pattern).
// 1D XCD grid: xcd = bid&7; s = bid>>3; m-tile = xcd*MPX + s/NT; n-tile = s%NT.
// MODE 0 (128x128): scatter q(b,h,t,d)[*1/sqrt(768)], k(b,h,t,d), vt(b,h,d,t)
// MODE 1 (128x128): +bias, relu -> f16 out [M][N]
// MODE 2 (64x64):   +bias +resid -> f32 out [M][N], no atomics, KSPLIT=1
template <int MODE, bool DBUF, int BK, int BM, int BN, int NT, int MPX>
__global__ __launch_bounds__(256) void gemm_kernel(
    const _Float16* __restrict__ A, const _Float16* __restrict__ Bt, int N, int K,
    const float* __restrict__ bias, const float* __restrict__ resid,
    float* __restrict__ outF, _Float16* __restrict__ outH,
    _Float16* __restrict__ qb, _Float16* __restrict__ kb, _Float16* __restrict__ vtb) {
    constexpr int NBUF = DBUF ? 2 : 1;
    constexpr int IM = BM / 32, JN = BN / 32;
    __shared__ __align__(16) _Float16 As[NBUF][BM * BK];
    __shared__ __align__(16) _Float16 Bs[NBUF][BN * BK];
    const int tid = threadIdx.x;
    const int wave = tid >> 6, lane = tid & 63;

    const int bid = blockIdx.x;
    const int xcd = bid & 7, s = bid >> 3;
    const int m0 = (xcd * MPX + s / NT) * BM;
    const int n0 = (s % NT) * BN;

    const int wm = (wave >> 1) * (BM / 2), wn = (wave & 1) * (BN / 2);
    const int lr = lane & 15, lq = lane >> 4;
    const int nIter = K / BK;

    auto stage = [&](int k0, int bsel) {
        if constexpr (BK == 32) {
            const int sr = lane >> 2;
            const int sc = (lane & 3) ^ ((lane >> 3) & 3);
#pragma unroll
            for (int t = 0; t < BM / 64; ++t) {
                int row = wave * (BM / 4) + t * 16;
                gld16(&A[(size_t)(m0 + row + sr) * K + k0 + sc * 8], &As[bsel][row * 32]);
            }
#pragma unroll
            for (int t = 0; t < BN / 64; ++t) {
                int row = wave * (BN / 4) + t * 16;
                gld16(&Bt[(size_t)(n0 + row + sr) * K + k0 + sc * 8], &Bs[bsel][row * 32]);
            }
        } else {
            const int sr8 = lane >> 3;                 // row within group of 8
            const int sc8 = (lane & 7) ^ sr8;          // swizzled 16B chunk
#pragma unroll
            for (int t = 0; t < BM / 32; ++t) {
                int row0 = wave * (BM / 4) + t * 8;
                gld16(&A[(size_t)(m0 + row0 + sr8) * K + k0 + sc8 * 8], &As[bsel][row0 * 64]);
            }
#pragma unroll
            for (int t = 0; t < BN / 32; ++t) {
                int row0 = wave * (BN / 4) + t * 8;
                gld16(&Bt[(size_t)(n0 + row0 + sr8) * K + k0 + sc8 * 8], &Bs[bsel][row0 * 64]);
            }
        }
    };

    auto compute = [&](int bsel, f32x4 (&acc)[IM][JN]) {
        if constexpr (BK == 32) {
            half8 af[IM], bf[JN];
            const int cs = (lq ^ ((lr >> 1) & 3)) * 8;
#pragma unroll
            for (int i = 0; i < IM; i++) af[i] = *(const half8*)&As[bsel][(wm + i * 16 + lr) * 32 + cs];
#pragma unroll
            for (int j = 0; j < JN; j++) bf[j] = *(const half8*)&Bs[bsel][(wn + j * 16 + lr) * 32 + cs];
#pragma unroll
            for (int i = 0; i < IM; i++)
#pragma unroll
                for (int j = 0; j < JN; j++)
                    acc[i][j] = mfma16(af[i], bf[j], acc[i][j]);
        } else {
#pragma unroll
            for (int ks = 0; ks < 2; ks++) {
                half8 af[IM], bf[JN];
                const int cs = ((ks * 4 + lq) ^ (lr & 7)) * 8;
#pragma unroll
                for (int i = 0; i < IM; i++) af[i] = *(const half8*)&As[bsel][(wm + i * 16 + lr) * 64 + cs];
#pragma unroll
                for (int j = 0; j < JN; j++) bf[j] = *(const half8*)&Bs[bsel][(wn + j * 16 + lr) * 64 + cs];
#pragma unroll
                for (int i = 0; i < IM; i++)
#pragma unroll
                    for (int j = 0; j < JN; j++)
                        acc[i][j] = mfma16(af[i], bf[j], acc[i][j]);
            }
        }
    };

    f32x4 acc[IM][JN] = {};

    if constexpr (DBUF) {
        stage(0, 0);
        for (int it = 0; it < nIter; ++it) {
            __syncthreads();                 // drains prefetch of tile it
            if (it + 1 < nIter) stage((it + 1) * BK, (it + 1) & 1);
            compute(it & 1, acc);
        }
    } else {
        for (int it = 0; it < nIter; ++it) {
            stage(it * BK, 0);
            __syncthreads();
            compute(0, acc);
            __syncthreads();
        }
    }

    const float qscale = 0.03608439182435161f;  // 1/sqrt(768)
#pragma unroll
    for (int i = 0; i < IM; i++) {
#pragma unroll
        for (int j = 0; j < JN; j++) {
            int n = n0 + wn + j * 16 + lr;
            int mb = m0 + wm + i * 16 + lq * 4;
#pragma unroll
            for (int r = 0; r < 4; r++) {
                int m = mb + r;
                float v = acc[i][j][r];
                if constexpr (MODE == 0) {
                    int b = m >> 11, t = m & 2047;
                    int sel = n / 768, nn = n % 768;
                    int h = nn >> 6, d = nn & 63;
                    size_t bh = (size_t)(b * 12 + h);
                    if (sel == 0)      qb[(bh * 2048 + t) * 64 + d] = (_Float16)(v * qscale);
                    else if (sel == 1) kb[(bh * 2048 + t) * 64 + d] = (_Float16)v;
                    else               vtb[(bh * 64 + d) * 2048 + t] = (_Float16)v;
                } else if constexpr (MODE == 1) {
                    v += bias[n];
                    v = v > 0.f ? v : 0.f;
                    outH[(size_t)m * N + n] = (_Float16)v;
                } else {
                    v += bias[n] + resid[(size_t)m * N + n];
                    outF[(size_t)m * N + n] = v;
                }
            }
        }
    }
}

// ---------------- flash attention (causal), persistent queue, in-register P ----
// Items: id even -> heavy qt = 31 - (id>>1)/24; id odd -> light qt = 15 - (id>>1)/24
// (both descending); bh = (id>>1) % 24. 768 items, 768 blocks (256 thr, 3/CU).
// r20: swapped QK^T (S = mfma(K,Q)): lane holds q=lr (col), k=nf*16+lq*4+r (row).
// exp in-register -> pa[nf] = half4 == A-frag of mfma_f32_16x16x16_f16
// (row=lane&15=q, k=(lane>>4)*4+e) -> PV with NO LDS transpose. V read as
// ds_read_b64: phys chunk (2nf+(lq>>1))^(lr&7), half-chunk (lq&1)*4.
// lsum: scalar per lane (q=lr); reduce xor16+xor32; redistribute via 4 shfl.
// Output store identical to r17 (q=lq*4+r row, d=df*16+lr col).
__global__ __launch_bounds__(256) void attn_kernel(const _Float16* __restrict__ qb,
                                                   const _Float16* __restrict__ kb,
                                                   const _Float16* __restrict__ vtb,
                                                   float* __restrict__ attn_out,
                                                   int* __restrict__ counter) {
    __shared__ __align__(16) _Float16 Ks[2][64 * 64];
    __shared__ __align__(16) _Float16 Vs[2][64 * 64];
    __shared__ int s_item;
    const int tid = threadIdx.x, wave = tid >> 6, lane = tid & 63;
    const int lr = lane & 15, lq = lane >> 4;
    const int sr = lane >> 3;            // staging row within 8
    const int sc = (lane & 7) ^ sr;      // swizzled chunk

    for (;;) {
        __syncthreads();                     // all waves done with LDS + s_item
        if (tid == 0) s_item = atomicAdd(counter, 1);
        __syncthreads();
        const int item = s_item;
        if (item >= 768) break;

        const int j = item >> 1;
        const int jq = j / 24;
        const int qt = (item & 1) ? (15 - jq) : (31 - jq);
        const int bh = j - jq * 24;
        const int b = bh / 12, h = bh % 12;
        const int q0 = qt * 64;

        const _Float16* qbase = qb + (size_t)bh * 2048 * 64;
        const _Float16* kbase = kb + (size_t)bh * 2048 * 64;
        const _Float16* vbase = vtb + (size_t)bh * 64 * 2048;

        half8 qf[2];
#pragma unroll
        for (int kd2 = 0; kd2 < 2; kd2++)
            qf[kd2] = *(const half8*)&qbase[(size_t)(q0 + wave * 16 + lr) * 64 + kd2 * 32 + lq * 8];

        auto stageKV = [&](int tile, int bsel) {
            int kv0 = tile << 6;
#pragma unroll
            for (int u = 0; u < 2; ++u) {
                int row0 = wave * 16 + u * 8;
                gld16(&kbase[(size_t)(kv0 + row0 + sr) * 64 + sc * 8], &Ks[bsel][row0 * 64]);
                gld16(&vbase[(size_t)(row0 + sr) * 2048 + kv0 + sc * 8], &Vs[bsel][row0 * 64]);
            }
        };

        f32x4 O[4] = {};
        float lsum = 0.f;
        const int nT = qt + 1;
        const int q_lane = q0 + wave * 16 + lr;   // this lane's q (swapped layout)
        stageKV(0, 0);

        for (int t = 0; t < nT; ++t) {
            __syncthreads();                      // drains glds for tile t
            if (t + 1 < nT) stageKV(t + 1, (t + 1) & 1);
            const int bs = t & 1, kv0 = t << 6;
            const bool mask = (t == qt);

            // S^T = K·Q^T : lane -> col q=lr, rows k = nf*16 + lq*4 + r
            f32x4 S[4] = {};
#pragma unroll
            for (int kd2 = 0; kd2 < 2; kd2++) {
#pragma unroll
                for (int nf = 0; nf < 4; nf++) {
                    half8 bk = *(const half8*)&Ks[bs][(nf * 16 + lr) * 64 +
                                                      (((kd2 * 4 + lq) ^ (lr & 7)) * 8)];
                    S[nf] = mfma16(bk, qf[kd2], S[nf]);   // swapped operands
                }
            }

            // exp + mask in-register; pa[nf] is directly the K=16 PV A-frag
            half4 pa[4];
#pragma unroll
            for (int nf = 0; nf < 4; nf++) {
#pragma unroll
                for (int r = 0; r < 4; r++) {
                    float p = __expf(S[nf][r]);
                    if (mask) {
                        int kidx = kv0 + nf * 16 + lq * 4 + r;
                        if (kidx > q_lane) p = 0.f;
                    }
                    lsum += p;
                    pa[nf][r] = (_Float16)p;
                }
            }

            // PV: O[q][d] += P·V, 16x16x16 MFMAs, V from swizzled Vs (V^T: [d][kv])
#pragma unroll
            for (int df = 0; df < 4; df++) {
#pragma unroll
                for (int nf = 0; nf < 4; nf++) {
                    const half4 bv = *(const half4*)&Vs[bs][(df * 16 + lr) * 64 +
                                                            (((2 * nf + (lq >> 1)) ^ (lr & 7)) * 8) +
                                                            (lq & 1) * 4];
                    O[df] = mfma16k16(pa[nf], bv, O[df]);
                }
            }
        }

        // reduce lsum over the 4 lanes sharing q=lr
        lsum += __shfl_xor(lsum, 16, 64);
        lsum += __shfl_xor(lsum, 32, 64);

#pragma unroll
        for (int df = 0; df < 4; df++) {
#pragma unroll
            for (int r = 0; r < 4; r++) {
                int t = q0 + wave * 16 + lq * 4 + r;
                int d = df * 16 + lr;
                float denom = __shfl(lsum, lq * 4 + r, 64);
                attn_out[((size_t)b * 2048 + t) * 768 + h * 64 + d] = O[df][r] / denom;
            }
        }
    }
}

extern "C" void kernel_launch(void* const* d_in, const int* in_sizes, int n_in,
                              void* d_out, int out_size, void* d_ws, size_t ws_size,
                              hipStream_t stream) {
    (void)in_sizes; (void)n_in; (void)out_size; (void)ws_size;
    const float* x        = (const float*)d_in[0];
    const float* ln1_g    = (const float*)d_in[1];
    const float* ln1_b    = (const float*)d_in[2];
    const float* wq       = (const float*)d_in[3];
    const float* wk       = (const float*)d_in[4];
    const float* wv       = (const float*)d_in[5];
    const float* ln2_g    = (const float*)d_in[6];
    const float* ln2_b    = (const float*)d_in[7];
    const float* w_hidden = (const float*)d_in[8];
    const float* b_hidden = (const float*)d_in[9];
    const float* w_proj   = (const float*)d_in[10];
    const float* b_proj   = (const float*)d_in[11];
    float* out = (float*)d_out;

    uint8_t* p = (uint8_t*)d_ws;
    _Float16* h1   = (_Float16*)p; p += 4096ull * 768 * 2;
    _Float16* wqkv = (_Float16*)p; p += 2304ull * 768 * 2;
    _Float16* wh   = (_Float16*)p; p += 3072ull * 768 * 2;
    _Float16* wp   = (_Float16*)p; p += 768ull * 3072 * 2;
    _Float16* qb   = (_Float16*)p; p += 24ull * 2048 * 64 * 2;
    _Float16* kb   = (_Float16*)p; p += 24ull * 2048 * 64 * 2;
    _Float16* vtb  = (_Float16*)p; p += 24ull * 2048 * 64 * 2;
    float*    attn = (float*)p;    p += 4096ull * 768 * 4;
    float*    x2   = (float*)p;    p += 4096ull * 768 * 4;
    _Float16* h2   = (_Float16*)p; p += 4096ull * 768 * 2;
    _Float16* hid  = (_Float16*)p; p += 4096ull * 3072 * 2;
    int*      ctr  = (int*)p;      p += 256;

    prep_kernel<<<10432, 256, 0, stream>>>(x, ln1_g, ln1_b, h1,
        wq, wk, wv, wqkv, w_hidden, wh, w_proj, wp, ctr);
    // MODE0: 32m x 18n (128x128), BK=32, DBUF (r17), XCD 1D grid 576
    gemm_kernel<0, true, 32, 128, 128, 18, 4><<<576, 256, 0, stream>>>(h1, wqkv, 2304, 768,
        nullptr, nullptr, nullptr, nullptr, qb, kb, vtb);
    // r20: 768 persistent 256-thread blocks (3/CU at 33KB LDS), in-register P
    attn_kernel<<<768, 256, 0, stream>>>(qb, kb, vtb, attn, ctr);
    addln_kernel<<<4096, 256, 0, stream>>>(x, attn, ln2_g, ln2_b, x2, h2);
    // MODE1: 32m x 24n (128x128), BK=32, XCD 1D grid 768
    gemm_kernel<1, true, 32, 128, 128, 24, 4><<<768, 256, 0, stream>>>(h2, wh, 3072, 768,
        b_hidden, nullptr, nullptr, hid, nullptr, nullptr, nullptr);
    // MODE2: 64m x 12n (64x64), BK=64 (r14: 96->48 iters), XCD 1D grid 768
    gemm_kernel<2, true, 64, 64, 64, 12, 8><<<768, 256, 0, stream>>>(hid, wp, 768, 3072,
        b_proj, x2, out, nullptr, nullptr, nullptr, nullptr);
}

// Round 9
// 243.627 us; speedup vs baseline: 1.0424x; 1.0161x over previous
//
#include <hip/hip_runtime.h>
#include <stdint.h>

// B=2, T=2048, C=768, H=12, D=64. All inputs fp32; output fp32.
// Internally: f16 MFMA (16x16x32), fp32 accumulation.
// GEMMs: glds width=16 staging, XOR-swizzled LDS (0 bank conflicts measured),
// XCD-aware 1D grids (r10: FETCH 83->31 MB on MODE2).
// MODE2 (r12): 64x64 tiles, no atomics; direct epilogue out = acc + b_proj + x2.
// r13: attn persistent + dynamic work queue.
// r14: MODE2 BK=64 (96->48 iters). PASSED 257.5us.
// r15/r16: CROSS-BLOCK split-KV FAILED twice (nondeterministic; banned).
// r17: MODE0 DBUF. PASSED 251.4us; attn 47.8us = heavy-item serial floor.
// r18: in-block split-KV REGRESSED (coupled barriers). r19: paired-tile
// barrier halving FLAT. r20: in-register P REGRESSED (ds_read_b64 V-frags
// 4-way bank-conflicted: SQ_LDS_BANK_CONFLICT 405K->3.24M; 2x PV issues).
// => r17 per-tile body is the proven optimum; structural rewrites 0-for-3.
// r21: attn = r17-exact body + descending-light decode + s_setprio(1) around
// MFMA clusters (T5: helps when co-resident blocks are at different phases —
// our persistent-queue attn is exactly that; +4-7% measured in that regime).

typedef __attribute__((ext_vector_type(8))) _Float16 half8;
typedef __attribute__((ext_vector_type(4))) float f32x4;

__device__ inline f32x4 mfma16(half8 a, half8 b, f32x4 c) {
    return __builtin_amdgcn_mfma_f32_16x16x32_f16(a, b, c, 0, 0, 0);
}

__device__ __forceinline__ void gld16(const _Float16* g, _Float16* lds) {
    __builtin_amdgcn_global_load_lds(
        (const __attribute__((address_space(1))) void*)(uintptr_t)g,
        (__attribute__((address_space(3))) void*)(uint32_t)(uintptr_t)lds,
        16, 0, 0);
}

// ---------------- fused prep: LN1 + all three weight repacks ----------------
// blocks [0,4096): ln rows; [4096,5824): qkv repack; [5824,8128): wh; [8128,10432): wp
__global__ __launch_bounds__(256) void prep_kernel(
    const float* __restrict__ x, const float* __restrict__ g, const float* __restrict__ bta,
    _Float16* __restrict__ h1,
    const float* __restrict__ wq, const float* __restrict__ wk, const float* __restrict__ wv,
    _Float16* __restrict__ wqkv,
    const float* __restrict__ w_hidden, _Float16* __restrict__ wh,
    const float* __restrict__ w_proj, _Float16* __restrict__ wp,
    int* __restrict__ ctr) {
    __shared__ float tile[32][33];
    int bid = blockIdx.x;
    int tid = threadIdx.x;
    if (bid == 0 && tid == 0) *ctr = 0;   // work-queue reset for attn_kernel
    if (bid < 4096) {
        int row = bid;
        const float* xr = x + (size_t)row * 768;
        float v[3], s = 0.f, s2 = 0.f;
#pragma unroll
        for (int i = 0; i < 3; i++) { v[i] = xr[tid + i * 256]; s += v[i]; s2 += v[i] * v[i]; }
#pragma unroll
        for (int off = 32; off; off >>= 1) { s += __shfl_down(s, off, 64); s2 += __shfl_down(s2, off, 64); }
        float* red = &tile[0][0];
        int wave = tid >> 6, lane = tid & 63;
        if (lane == 0) { red[wave] = s; red[4 + wave] = s2; }
        __syncthreads();
        if (tid == 0) {
            float ts = red[0] + red[1] + red[2] + red[3];
            float ts2 = red[4] + red[5] + red[6] + red[7];
            float mu = ts * (1.f / 768.f);
            float var = ts2 * (1.f / 768.f) - mu * mu;
            red[0] = mu; red[1] = rsqrtf(var + 1e-5f);
        }
        __syncthreads();
        float mu = red[0], rstd = red[1];
#pragma unroll
        for (int i = 0; i < 3; i++) {
            int c = tid + i * 256;
            h1[(size_t)row * 768 + c] = (_Float16)((v[i] - mu) * rstd * g[c] + bta[c]);
        }
        return;
    }
    int tx = tid & 31, ty = tid >> 5;
    if (bid < 5824) {
        int idx = bid - 4096;
        int y = idx / 24, bx = idx % 24;
        int sel = y / 24, rem = y % 24, h = rem >> 1, dt = rem & 1;
        const float* src = (sel == 0) ? wq : ((sel == 1) ? wk : wv);
        int c0 = bx * 32, d0 = dt * 32;
#pragma unroll
        for (int i = 0; i < 4; i++) {
            int c = ty + i * 8;
            tile[c][tx] = src[((size_t)h * 768 + c0 + c) * 64 + d0 + tx];
        }
        __syncthreads();
#pragma unroll
        for (int i = 0; i < 4; i++) {
            int d = ty + i * 8;
            wqkv[((size_t)(sel * 768 + h * 64 + d0 + d)) * 768 + c0 + tx] = (_Float16)tile[tx][d];
        }
        return;
    }
    const float* w; _Float16* wt; int K, N, idx;
    if (bid < 8128) { idx = bid - 5824; w = w_hidden; wt = wh; K = 768; N = 3072; }
    else            { idx = bid - 8128; w = w_proj;   wt = wp; K = 3072; N = 768; }
    int nb = N / 32;
    int n0 = (idx % nb) * 32, k0 = (idx / nb) * 32;
#pragma unroll
    for (int i = 0; i < 4; i++) {
        int k = ty + i * 8;
        tile[k][tx] = w[(size_t)(k0 + k) * N + n0 + tx];
    }
    __syncthreads();
#pragma unroll
    for (int i = 0; i < 4; i++) {
        int n = ty + i * 8;
        wt[(size_t)(n0 + n) * K + k0 + tx] = (_Float16)tile[tx][n];
    }
}

// x2 = x + attn; h2 = LN(x2)   (x2 is MODE2's residual input)
__global__ __launch_bounds__(256) void addln_kernel(const float* __restrict__ x,
                                                    const float* __restrict__ attn,
                                                    const float* __restrict__ g,
                                                    const float* __restrict__ bta,
                                                    float* __restrict__ x2,
                                                    _Float16* __restrict__ out) {
    int row = blockIdx.x;               // b*2048 + t
    const float* xr = x + (size_t)row * 768;
    const float* ar = attn + (size_t)row * 768;
    int tid = threadIdx.x;
    float v[3], s = 0.f, s2 = 0.f;
#pragma unroll
    for (int i = 0; i < 3; i++) {
        int c = tid + i * 256;
        v[i] = xr[c] + ar[c];
        x2[(size_t)row * 768 + c] = v[i];
        s += v[i]; s2 += v[i] * v[i];
    }
#pragma unroll
    for (int off = 32; off; off >>= 1) { s += __shfl_down(s, off, 64); s2 += __shfl_down(s2, off, 64); }
    __shared__ float red[8];
    int wave = tid >> 6, lane = tid & 63;
    if (lane == 0) { red[wave] = s; red[4 + wave] = s2; }
    __syncthreads();
    if (tid == 0) {
        float ts = red[0] + red[1] + red[2] + red[3];
        float ts2 = red[4] + red[5] + red[6] + red[7];
        float mu = ts * (1.f / 768.f);
        float var = ts2 * (1.f / 768.f) - mu * mu;
        red[0] = mu; red[1] = rsqrtf(var + 1e-5f);
    }
    __syncthreads();
    float mu = red[0], rstd = red[1];
#pragma unroll
    for (int i = 0; i < 3; i++) {
        int c = tid + i * 256;
        out[(size_t)row * 768 + c] = (_Float16)((v[i] - mu) * rstd * g[c] + bta[c]);
    }
}

// ---------------- MFMA GEMM BMxBN tile, BK templated, glds staging ----------------
// BK=32 LDS: row = 4 chunks of 16B, phys chunk = c ^ ((row>>1)&3)  (0 conflicts, r3).
// BK=64 LDS: row = 8 chunks of 16B, phys chunk = c ^ (row&7)  (attn-proven pattern).
// 1D XCD grid: xcd = bid&7; s = bid>>3; m-tile = xcd*MPX + s/NT; n-tile = s%NT.
// MODE 0 (128x128): scatter q(b,h,t,d)[*1/sqrt(768)], k(b,h,t,d), vt(b,h,d,t)
// MODE 1 (128x128): +bias, relu -> f16 out [M][N]
// MODE 2 (64x64):   +bias +resid -> f32 out [M][N], no atomics, KSPLIT=1
template <int MODE, bool DBUF, int BK, int BM, int BN, int NT, int MPX>
__global__ __launch_bounds__(256) void gemm_kernel(
    const _Float16* __restrict__ A, const _Float16* __restrict__ Bt, int N, int K,
    const float* __restrict__ bias, const float* __restrict__ resid,
    float* __restrict__ outF, _Float16* __restrict__ outH,
    _Float16* __restrict__ qb, _Float16* __restrict__ kb, _Float16* __restrict__ vtb) {
    constexpr int NBUF = DBUF ? 2 : 1;
    constexpr int IM = BM / 32, JN = BN / 32;
    __shared__ __align__(16) _Float16 As[NBUF][BM * BK];
    __shared__ __align__(16) _Float16 Bs[NBUF][BN * BK];
    const int tid = threadIdx.x;
    const int wave = tid >> 6, lane = tid & 63;

    const int bid = blockIdx.x;
    const int xcd = bid & 7, s = bid >> 3;
    const int m0 = (xcd * MPX + s / NT) * BM;
    const int n0 = (s % NT) * BN;

    const int wm = (wave >> 1) * (BM / 2), wn = (wave & 1) * (BN / 2);
    const int lr = lane & 15, lq = lane >> 4;
    const int nIter = K / BK;

    auto stage = [&](int k0, int bsel) {
        if constexpr (BK == 32) {
            const int sr = lane >> 2;
            const int sc = (lane & 3) ^ ((lane >> 3) & 3);
#pragma unroll
            for (int t = 0; t < BM / 64; ++t) {
                int row = wave * (BM / 4) + t * 16;
                gld16(&A[(size_t)(m0 + row + sr) * K + k0 + sc * 8], &As[bsel][row * 32]);
            }
#pragma unroll
            for (int t = 0; t < BN / 64; ++t) {
                int row = wave * (BN / 4) + t * 16;
                gld16(&Bt[(size_t)(n0 + row + sr) * K + k0 + sc * 8], &Bs[bsel][row * 32]);
            }
        } else {
            const int sr8 = lane >> 3;                 // row within group of 8
            const int sc8 = (lane & 7) ^ sr8;          // swizzled 16B chunk
#pragma unroll
            for (int t = 0; t < BM / 32; ++t) {
                int row0 = wave * (BM / 4) + t * 8;
                gld16(&A[(size_t)(m0 + row0 + sr8) * K + k0 + sc8 * 8], &As[bsel][row0 * 64]);
            }
#pragma unroll
            for (int t = 0; t < BN / 32; ++t) {
                int row0 = wave * (BN / 4) + t * 8;
                gld16(&Bt[(size_t)(n0 + row0 + sr8) * K + k0 + sc8 * 8], &Bs[bsel][row0 * 64]);
            }
        }
    };

    auto compute = [&](int bsel, f32x4 (&acc)[IM][JN]) {
        if constexpr (BK == 32) {
            half8 af[IM], bf[JN];
            const int cs = (lq ^ ((lr >> 1) & 3)) * 8;
#pragma unroll
            for (int i = 0; i < IM; i++) af[i] = *(const half8*)&As[bsel][(wm + i * 16 + lr) * 32 + cs];
#pragma unroll
            for (int j = 0; j < JN; j++) bf[j] = *(const half8*)&Bs[bsel][(wn + j * 16 + lr) * 32 + cs];
#pragma unroll
            for (int i = 0; i < IM; i++)
#pragma unroll
                for (int j = 0; j < JN; j++)
                    acc[i][j] = mfma16(af[i], bf[j], acc[i][j]);
        } else {
#pragma unroll
            for (int ks = 0; ks < 2; ks++) {
                half8 af[IM], bf[JN];
                const int cs = ((ks * 4 + lq) ^ (lr & 7)) * 8;
#pragma unroll
                for (int i = 0; i < IM; i++) af[i] = *(const half8*)&As[bsel][(wm + i * 16 + lr) * 64 + cs];
#pragma unroll
                for (int j = 0; j < JN; j++) bf[j] = *(const half8*)&Bs[bsel][(wn + j * 16 + lr) * 64 + cs];
#pragma unroll
                for (int i = 0; i < IM; i++)
#pragma unroll
                    for (int j = 0; j < JN; j++)
                        acc[i][j] = mfma16(af[i], bf[j], acc[i][j]);
            }
        }
    };

    f32x4 acc[IM][JN] = {};

    if constexpr (DBUF) {
        stage(0, 0);
        for (int it = 0; it < nIter; ++it) {
            __syncthreads();                 // drains prefetch of tile it
            if (it + 1 < nIter) stage((it + 1) * BK, (it + 1) & 1);
            compute(it & 1, acc);
        }
    } else {
        for (int it = 0; it < nIter; ++it) {
            stage(it * BK, 0);
            __syncthreads();
            compute(0, acc);
            __syncthreads();
        }
    }

    const float qscale = 0.03608439182435161f;  // 1/sqrt(768)
#pragma unroll
    for (int i = 0; i < IM; i++) {
#pragma unroll
        for (int j = 0; j < JN; j++) {
            int n = n0 + wn + j * 16 + lr;
            int mb = m0 + wm + i * 16 + lq * 4;
#pragma unroll
            for (int r = 0; r < 4; r++) {
                int m = mb + r;
                float v = acc[i][j][r];
                if constexpr (MODE == 0) {
                    int b = m >> 11, t = m & 2047;
                    int sel = n / 768, nn = n % 768;
                    int h = nn >> 6, d = nn & 63;
                    size_t bh = (size_t)(b * 12 + h);
                    if (sel == 0)      qb[(bh * 2048 + t) * 64 + d] = (_Float16)(v * qscale);
                    else if (sel == 1) kb[(bh * 2048 + t) * 64 + d] = (_Float16)v;
                    else               vtb[(bh * 64 + d) * 2048 + t] = (_Float16)v;
                } else if constexpr (MODE == 1) {
                    v += bias[n];
                    v = v > 0.f ? v : 0.f;
                    outH[(size_t)m * N + n] = (_Float16)v;
                } else {
                    v += bias[n] + resid[(size_t)m * N + n];
                    outF[(size_t)m * N + n] = v;
                }
            }
        }
    }
}

// ---------------- flash attention (causal), persistent + dynamic queue ----------------
// Items: id even -> heavy qt = 31 - (id>>1)/24; id odd -> light qt = 15 - (id>>1)/24
// (both descending); bh = (id>>1) % 24. 768 items, 512 blocks pull via atomic.
// r21: r17-exact per-tile body (proven fastest: 47.8us) + s_setprio(1) around
// MFMA clusters (helps when co-resident blocks run different phases).
__global__ __launch_bounds__(256) void attn_kernel(const _Float16* __restrict__ qb,
                                                   const _Float16* __restrict__ kb,
                                                   const _Float16* __restrict__ vtb,
                                                   float* __restrict__ attn_out,
                                                   int* __restrict__ counter) {
    __shared__ __align__(16) _Float16 Ks[2][64 * 64];
    __shared__ __align__(16) _Float16 Vs[2][64 * 64];
    __shared__ __align__(16) _Float16 Ps[4][16 * 72];
    __shared__ int s_item;
    const int tid = threadIdx.x, wave = tid >> 6, lane = tid & 63;
    const int lr = lane & 15, lq = lane >> 4;
    const int sr = lane >> 3;            // staging row within 8
    const int sc = (lane & 7) ^ sr;      // swizzled chunk

    for (;;) {
        __syncthreads();                     // all waves done with LDS + s_item
        if (tid == 0) s_item = atomicAdd(counter, 1);
        __syncthreads();
        const int item = s_item;
        if (item >= 768) break;

        const int j = item >> 1;
        const int jq = j / 24;
        const int qt = (item & 1) ? (15 - jq) : (31 - jq);
        const int bh = j - jq * 24;
        const int b = bh / 12, h = bh % 12;
        const int q0 = qt * 64;

        const _Float16* qbase = qb + (size_t)bh * 2048 * 64;
        const _Float16* kbase = kb + (size_t)bh * 2048 * 64;
        const _Float16* vbase = vtb + (size_t)bh * 64 * 2048;

        half8 qf[2];
#pragma unroll
        for (int kd2 = 0; kd2 < 2; kd2++)
            qf[kd2] = *(const half8*)&qbase[(size_t)(q0 + wave * 16 + lr) * 64 + kd2 * 32 + lq * 8];

        auto stageKV = [&](int tile, int bsel) {
            int kv0 = tile << 6;
#pragma unroll
            for (int u = 0; u < 2; ++u) {
                int row0 = wave * 16 + u * 8;
                gld16(&kbase[(size_t)(kv0 + row0 + sr) * 64 + sc * 8], &Ks[bsel][row0 * 64]);
                gld16(&vbase[(size_t)(row0 + sr) * 2048 + kv0 + sc * 8], &Vs[bsel][row0 * 64]);
            }
        };

        f32x4 O[4] = {};
        float lsum[4] = {0.f, 0.f, 0.f, 0.f};
        const int nT = qt + 1;
        stageKV(0, 0);

        for (int t = 0; t < nT; ++t) {
            __syncthreads();                      // drains glds for tile t
            if (t + 1 < nT) stageKV(t + 1, (t + 1) & 1);
            const int bs = t & 1, kv0 = t << 6;
            const bool mask = (t == qt);

            f32x4 S[4] = {};
            __builtin_amdgcn_s_setprio(1);
#pragma unroll
            for (int kd2 = 0; kd2 < 2; kd2++) {
#pragma unroll
                for (int nf = 0; nf < 4; nf++) {
                    half8 bk = *(const half8*)&Ks[bs][(nf * 16 + lr) * 64 +
                                                      (((kd2 * 4 + lq) ^ (lr & 7)) * 8)];
                    S[nf] = mfma16(qf[kd2], bk, S[nf]);
                }
            }
            __builtin_amdgcn_s_setprio(0);

            const int qi_base = q0 + wave * 16 + lq * 4;
#pragma unroll
            for (int r = 0; r < 4; r++) {
                float a = 0.f;
#pragma unroll
                for (int nf = 0; nf < 4; nf++) {
                    float p = __expf(S[nf][r]);
                    if (mask) {
                        int kidx = kv0 + nf * 16 + lr;
                        if (kidx > qi_base + r) p = 0.f;
                    }
                    a += p;
                    Ps[wave][(lq * 4 + r) * 72 + nf * 16 + lr] = (_Float16)p;
                }
                lsum[r] += a;
            }

            __builtin_amdgcn_s_setprio(1);
#pragma unroll
            for (int ks = 0; ks < 2; ks++) {
                half8 ap = *(const half8*)&Ps[wave][lr * 72 + ks * 32 + lq * 8];
#pragma unroll
                for (int df = 0; df < 4; df++) {
                    half8 bv = *(const half8*)&Vs[bs][(df * 16 + lr) * 64 +
                                                      (((ks * 4 + lq) ^ (lr & 7)) * 8)];
                    O[df] = mfma16(ap, bv, O[df]);
                }
            }
            __builtin_amdgcn_s_setprio(0);
        }

#pragma unroll
        for (int r = 0; r < 4; r++) {
#pragma unroll
            for (int off = 1; off < 16; off <<= 1) lsum[r] += __shfl_xor(lsum[r], off, 64);
        }

#pragma unroll
        for (int df = 0; df < 4; df++) {
#pragma unroll
            for (int r = 0; r < 4; r++) {
                int t = q0 + wave * 16 + lq * 4 + r;
                int d = df * 16 + lr;
                attn_out[((size_t)b * 2048 + t) * 768 + h * 64 + d] = O[df][r] / lsum[r];
            }
        }
    }
}

extern "C" void kernel_launch(void* const* d_in, const int* in_sizes, int n_in,
                              void* d_out, int out_size, void* d_ws, size_t ws_size,
                              hipStream_t stream) {
    (void)in_sizes; (void)n_in; (void)out_size; (void)ws_size;
    const float* x        = (const float*)d_in[0];
    const float* ln1_g    = (const float*)d_in[1];
    const float* ln1_b    = (const float*)d_in[2];
    const float* wq       = (const float*)d_in[3];
    const float* wk       = (const float*)d_in[4];
    const float* wv       = (const float*)d_in[5];
    const float* ln2_g    = (const float*)d_in[6];
    const float* ln2_b    = (const float*)d_in[7];
    const float* w_hidden = (const float*)d_in[8];
    const float* b_hidden = (const float*)d_in[9];
    const float* w_proj   = (const float*)d_in[10];
    const float* b_proj   = (const float*)d_in[11];
    float* out = (float*)d_out;

    uint8_t* p = (uint8_t*)d_ws;
    _Float16* h1   = (_Float16*)p; p += 4096ull * 768 * 2;
    _Float16* wqkv = (_Float16*)p; p += 2304ull * 768 * 2;
    _Float16* wh   = (_Float16*)p; p += 3072ull * 768 * 2;
    _Float16* wp   = (_Float16*)p; p += 768ull * 3072 * 2;
    _Float16* qb   = (_Float16*)p; p += 24ull * 2048 * 64 * 2;
    _Float16* kb   = (_Float16*)p; p += 24ull * 2048 * 64 * 2;
    _Float16* vtb  = (_Float16*)p; p += 24ull * 2048 * 64 * 2;
    float*    attn = (float*)p;    p += 4096ull * 768 * 4;
    float*    x2   = (float*)p;    p += 4096ull * 768 * 4;
    _Float16* h2   = (_Float16*)p; p += 4096ull * 768 * 2;
    _Float16* hid  = (_Float16*)p; p += 4096ull * 3072 * 2;
    int*      ctr  = (int*)p;      p += 256;

    prep_kernel<<<10432, 256, 0, stream>>>(x, ln1_g, ln1_b, h1,
        wq, wk, wv, wqkv, w_hidden, wh, w_proj, wp, ctr);
    // MODE0: 32m x 18n (128x128), BK=32, DBUF (r17), XCD 1D grid 576
    gemm_kernel<0, true, 32, 128, 128, 18, 4><<<576, 256, 0, stream>>>(h1, wqkv, 2304, 768,
        nullptr, nullptr, nullptr, nullptr, qb, kb, vtb);
    // r21: 512 persistent 256-thread blocks (2/CU), r17 body + setprio
    attn_kernel<<<512, 256, 0, stream>>>(qb, kb, vtb, attn, ctr);
    addln_kernel<<<4096, 256, 0, stream>>>(x, attn, ln2_g, ln2_b, x2, h2);
    // MODE1: 32m x 24n (128x128), BK=32, XCD 1D grid 768
    gemm_kernel<1, true, 32, 128, 128, 24, 4><<<768, 256, 0, stream>>>(h2, wh, 3072, 768,
        b_hidden, nullptr, nullptr, hid, nullptr, nullptr, nullptr);
    // MODE2: 64m x 12n (64x64), BK=64 (r14: 96->48 iters), XCD 1D grid 768
    gemm_kernel<2, true, 64, 64, 64, 12, 8><<<768, 256, 0, stream>>>(hid, wp, 768, 3072,
        b_proj, x2, out, nullptr, nullptr, nullptr, nullptr);
}